// Round 5
// baseline (21.374 us; speedup 1.0000x reference)
//
#include <hip/hip_runtime.h>

#define BB   256
#define NN   128
#define AA   15
#define HH   32
#define MIDD 256

// spin barrier among a subset of waves (only that subset touches ctr)
__device__ __forceinline__ void lds_arrive_wait(int* ctr, int target) {
    __threadfence_block();
    if ((threadIdx.x & 63) == 0) atomicAdd(ctr, 1);
    while (__hip_atomic_load(ctr, __ATOMIC_ACQUIRE, __HIP_MEMORY_SCOPE_WORKGROUP) < target)
        __builtin_amdgcn_s_sleep(1);
    __threadfence_block();
}

// aux_s layout: [0:128) mw1 | [128:224) aw1(rows0-2) | [224:256) ab1
//               [256:288) aw2 | [288:320) mw2 | [320:352) mb1 | [352] mb2 | [353] ab2
__global__ __launch_bounds__(512, 4) void gacq_v5(
    const float* __restrict__ obs,
    const float* __restrict__ mw1, const float* __restrict__ mb1,
    const float* __restrict__ mw2, const float* __restrict__ mb2,
    const float* __restrict__ aw1, const float* __restrict__ ab1,
    const float* __restrict__ aw2, const float* __restrict__ ab2,
    const float* __restrict__ cw1, const float* __restrict__ cb1,
    const float* __restrict__ cw2, const float* __restrict__ cb2,
    const float* __restrict__ cw3, const float* __restrict__ cb3,
    const float* __restrict__ cw4, const float* __restrict__ cb4,
    float* __restrict__ out)
{
    __shared__ __align__(16) float aux_s[356];
    __shared__ __align__(16) float obs_s[NN];
    __shared__ __align__(16) float v_s[NN][HH];    // 16 KB
    __shared__ __align__(16) float p_s[NN][HH];    // 16 KB, chunk-XOR swizzled
    __shared__ __align__(16) float h_s[2][MIDD];
    __shared__ float redc_s[4];
    __shared__ int vbar, cbar;

    const int b    = blockIdx.x;
    const int t    = threadIdx.x;
    const int lane = t & 63;
    const int w    = t >> 6;

    if (t == 0) { vbar = 0; cbar = 0; }
    if (t < 354) {
        float v;
        if      (t < 128) v = mw1[t];
        else if (t < 224) v = aw1[t - 128];
        else if (t < 256) v = ab1[t - 224];
        else if (t < 288) v = aw2[t - 256];
        else if (t < 320) v = mw2[t - 288];
        else if (t < 352) v = mb1[t - 320];
        else if (t == 352) v = mb2[0];
        else               v = ab2[0];
        aux_s[t] = v;
    }
    if (t < NN) obs_s[t] = obs[b * NN + t];
    __syncthreads();   // join #1

    if (w < 4) {
        // ==================== messenger waves (barrier-free path) ====================
        // each wave owns rows [32w, 32w+32)
        const int   prow  = w * 32 + (lane >> 1);
        const int   cbase = (lane & 1) * 4;           // chunks cbase..cbase+3
        const float pobs  = obs_s[prow];
        const float pcoor = (float)prow * (1.0f / (float)NN);

        // v rows for this wave: v[prow][k] = obs*mw1[2][k] + coor*mw1[3][k] + mb1[k]
#pragma unroll
        for (int cc = 0; cc < 4; ++cc) {
            const int k0 = (cbase + cc) * 4;
            float4 vv;
            vv.x = pobs * aux_s[64 + k0 + 0] + pcoor * aux_s[96 + k0 + 0] + aux_s[320 + k0 + 0];
            vv.y = pobs * aux_s[64 + k0 + 1] + pcoor * aux_s[96 + k0 + 1] + aux_s[320 + k0 + 1];
            vv.z = pobs * aux_s[64 + k0 + 2] + pcoor * aux_s[96 + k0 + 2] + aux_s[320 + k0 + 2];
            vv.w = pobs * aux_s[64 + k0 + 3] + pcoor * aux_s[96 + k0 + 3] + aux_s[320 + k0 + 3];
            *(float4*)&v_s[prow][k0] = vv;
        }
        lds_arrive_wait(&vbar, 4);   // all v rows ready (msg waves only)

        // stage 1: thread = (kg = lane&7 -> 4 k's, rsub = lane>>3 -> 4 rows)
        const int kg   = lane & 7;
        const int rsub = lane >> 3;
        const int r0   = w * 32 + rsub * 4;

        float u[4][4];
        const float w20 = aux_s[288 + kg * 4 + 0];
        const float w21 = aux_s[288 + kg * 4 + 1];
        const float w22 = aux_s[288 + kg * 4 + 2];
        const float w23 = aux_s[288 + kg * 4 + 3];
#pragma unroll
        for (int rr = 0; rr < 4; ++rr) {
            const int   row = r0 + rr;
            const float ob  = obs_s[row];
            const float cr  = (float)row * (1.0f / (float)NN);
#pragma unroll
            for (int kk = 0; kk < 4; ++kk)
                u[rr][kk] = ob * aux_s[kg * 4 + kk] + cr * aux_s[32 + kg * 4 + kk];
        }

        float acc0 = 0.f, acc1 = 0.f, acc2 = 0.f, acc3 = 0.f;
        const float* vbase = &v_s[0][kg * 4];
        float4 vc = *(const float4*)(vbase);
#pragma unroll 4
        for (int j = 0; j < 128; ++j) {
            const float4 vn = *(const float4*)(vbase + ((j + 1) & 127) * HH);
            acc0 += fmaxf(u[0][0] + vc.x, 0.f) * w20;
            acc1 += fmaxf(u[1][0] + vc.x, 0.f) * w20;
            acc2 += fmaxf(u[2][0] + vc.x, 0.f) * w20;
            acc3 += fmaxf(u[3][0] + vc.x, 0.f) * w20;
            acc0 += fmaxf(u[0][1] + vc.y, 0.f) * w21;
            acc1 += fmaxf(u[1][1] + vc.y, 0.f) * w21;
            acc2 += fmaxf(u[2][1] + vc.y, 0.f) * w21;
            acc3 += fmaxf(u[3][1] + vc.y, 0.f) * w21;
            acc0 += fmaxf(u[0][2] + vc.z, 0.f) * w22;
            acc1 += fmaxf(u[1][2] + vc.z, 0.f) * w22;
            acc2 += fmaxf(u[2][2] + vc.z, 0.f) * w22;
            acc3 += fmaxf(u[3][2] + vc.z, 0.f) * w22;
            acc0 += fmaxf(u[0][3] + vc.w, 0.f) * w23;
            acc1 += fmaxf(u[1][3] + vc.w, 0.f) * w23;
            acc2 += fmaxf(u[2][3] + vc.w, 0.f) * w23;
            acc3 += fmaxf(u[3][3] + vc.w, 0.f) * w23;
            vc = vn;
        }
        // butterfly over kg (lane bits 0-2): every lane gets the k-sum for its 4 rows
#pragma unroll
        for (int m = 1; m <= 4; m <<= 1) {
            acc0 += __shfl_xor(acc0, m);
            acc1 += __shfl_xor(acc1, m);
            acc2 += __shfl_xor(acc2, m);
            acc3 += __shfl_xor(acc3, m);
        }
        // broadcast msg to this lane's p-row: row prow -> rsub' = lane>>3? no: prow's holder
        const int   src = lane & 56;            // a lane whose rsub == prow's rsub group
        const float m0  = __shfl(acc0, src);
        const float m1  = __shfl(acc1, src);
        const float m2  = __shfl(acc2, src);
        const float m3  = __shfl(acc3, src);
        const int   rrs = (lane >> 1) & 3;
        float mi = (rrs == 0) ? m0 : (rrs == 1) ? m1 : (rrs == 2) ? m2 : m3;
        mi += (float)NN * aux_s[352];

        // p-stage: p[prow][k] = mi*aw1[0][k] + coor*aw1[1][k] + ab1[k], swizzled store
        const int sw = prow & 7;
#pragma unroll
        for (int cc = 0; cc < 4; ++cc) {
            const int c  = cbase + cc;
            const int k0 = c * 4;
            float4 p;
            p.x = mi * aux_s[128 + k0 + 0] + pcoor * aux_s[160 + k0 + 0] + aux_s[224 + k0 + 0];
            p.y = mi * aux_s[128 + k0 + 1] + pcoor * aux_s[160 + k0 + 1] + aux_s[224 + k0 + 1];
            p.z = mi * aux_s[128 + k0 + 2] + pcoor * aux_s[160 + k0 + 2] + aux_s[224 + k0 + 2];
            p.w = mi * aux_s[128 + k0 + 3] + pcoor * aux_s[160 + k0 + 3] + aux_s[224 + k0 + 3];
            *(float4*)&p_s[prow][(c ^ sw) * 4] = p;
        }
    } else {
        // ==================== critic waves (spin-synced among themselves) ====================
        const int ct = t - 256;   // 0..255 = output unit
        {   // layer 1: 128 -> 256
            float a0 = 0.f, a1 = 0.f, a2 = 0.f, a3 = 0.f;
#pragma unroll 8
            for (int k = 0; k < NN; k += 4) {
                a0 += obs_s[k + 0] * cw1[(k + 0) * MIDD + ct];
                a1 += obs_s[k + 1] * cw1[(k + 1) * MIDD + ct];
                a2 += obs_s[k + 2] * cw1[(k + 2) * MIDD + ct];
                a3 += obs_s[k + 3] * cw1[(k + 3) * MIDD + ct];
            }
            h_s[0][ct] = fmaxf(cb1[ct] + ((a0 + a1) + (a2 + a3)), 0.f);
        }
        lds_arrive_wait(&cbar, 4);
        {   // layer 2: 256 -> 256
            float a0 = 0.f, a1 = 0.f, a2 = 0.f, a3 = 0.f;
#pragma unroll 8
            for (int k = 0; k < MIDD; k += 4) {
                a0 += h_s[0][k + 0] * cw2[(k + 0) * MIDD + ct];
                a1 += h_s[0][k + 1] * cw2[(k + 1) * MIDD + ct];
                a2 += h_s[0][k + 2] * cw2[(k + 2) * MIDD + ct];
                a3 += h_s[0][k + 3] * cw2[(k + 3) * MIDD + ct];
            }
            h_s[1][ct] = fmaxf(cb2[ct] + ((a0 + a1) + (a2 + a3)), 0.f);
        }
        lds_arrive_wait(&cbar, 8);
        {   // layer 3 + head
            float a0 = 0.f, a1 = 0.f, a2 = 0.f, a3 = 0.f;
#pragma unroll 8
            for (int k = 0; k < MIDD; k += 4) {
                a0 += h_s[1][k + 0] * cw3[(k + 0) * MIDD + ct];
                a1 += h_s[1][k + 1] * cw3[(k + 1) * MIDD + ct];
                a2 += h_s[1][k + 2] * cw3[(k + 2) * MIDD + ct];
                a3 += h_s[1][k + 3] * cw3[(k + 3) * MIDD + ct];
            }
            const float h3 = fmaxf(cb3[ct] + ((a0 + a1) + (a2 + a3)), 0.f);
            float pv = h3 * cw4[ct];
#pragma unroll
            for (int off = 32; off > 0; off >>= 1) pv += __shfl_xor(pv, off);
            if (lane == 0) redc_s[w - 4] = pv;
        }
        lds_arrive_wait(&cbar, 12);
        if (ct == 0)
            out[BB * AA + b] = redc_s[0] + redc_s[1] + redc_s[2] + redc_s[3] + cb4[0];
    }
    __syncthreads();   // join #2 (single call site, all 512 threads)

    // ==================== stage 2: actor logits, all 512 threads ====================
    {
        const int   a   = t >> 5;          // 16 groups, a==15 dummy
        const int   sub = t & 31;
        const float fa  = (float)a;
        float qa[HH];
#pragma unroll
        for (int k = 0; k < HH; ++k) qa[k] = fa * aux_s[192 + k];
        float s0 = 0.f, s1 = 0.f, s2 = 0.f, s3 = 0.f;
#pragma unroll
        for (int m = 0; m < 4; ++m) {
            const int row = sub + 32 * m;
            const int sw  = row & 7;
#pragma unroll
            for (int c = 0; c < 8; ++c) {
                const float4 p4 = *(const float4*)&p_s[row][(c ^ sw) * 4];
                const float4 w4 = *(const float4*)&aux_s[256 + c * 4];
                const int    k0 = c * 4;
                s0 += fmaxf(p4.x + qa[k0 + 0], 0.f) * w4.x;
                s1 += fmaxf(p4.y + qa[k0 + 1], 0.f) * w4.y;
                s2 += fmaxf(p4.z + qa[k0 + 2], 0.f) * w4.z;
                s3 += fmaxf(p4.w + qa[k0 + 3], 0.f) * w4.w;
            }
        }
        float s = (s0 + s1) + (s2 + s3);
#pragma unroll
        for (int off = 1; off < 32; off <<= 1) s += __shfl_xor(s, off);
        if (sub == 0 && a < AA)
            out[b * AA + a] = s + (float)NN * aux_s[353];
    }
}

extern "C" void kernel_launch(void* const* d_in, const int* in_sizes, int n_in,
                              void* d_out, int out_size, void* d_ws, size_t ws_size,
                              hipStream_t stream) {
    const float* obs = (const float*)d_in[0];
    const float* mw1 = (const float*)d_in[1];
    const float* mb1 = (const float*)d_in[2];
    const float* mw2 = (const float*)d_in[3];
    const float* mb2 = (const float*)d_in[4];
    const float* aw1 = (const float*)d_in[5];
    const float* ab1 = (const float*)d_in[6];
    const float* aw2 = (const float*)d_in[7];
    const float* ab2 = (const float*)d_in[8];
    const float* cw1 = (const float*)d_in[9];
    const float* cb1 = (const float*)d_in[10];
    const float* cw2 = (const float*)d_in[11];
    const float* cb2 = (const float*)d_in[12];
    const float* cw3 = (const float*)d_in[13];
    const float* cb3 = (const float*)d_in[14];
    const float* cw4 = (const float*)d_in[15];
    const float* cb4 = (const float*)d_in[16];
    float* out = (float*)d_out;

    gacq_v5<<<dim3(BB), dim3(512), 0, stream>>>(
        obs, mw1, mb1, mw2, mb2, aw1, ab1, aw2, ab2,
        cw1, cb1, cw2, cb2, cw3, cb3, cw4, cb4, out);
}

// Round 6
// 17.492 us; speedup vs baseline: 1.2219x; 1.2219x over previous
//
#include <hip/hip_runtime.h>

#define BB   256
#define NN   128
#define AA   15
#define HH   32
#define MIDD 256

#if defined(__has_builtin)
#if __has_builtin(__builtin_amdgcn_fdot2) && __has_builtin(__builtin_elementwise_max)
#define USE_F16DOT 1
#endif
#endif

#ifdef USE_F16DOT
typedef _Float16 h2_t __attribute__((ext_vector_type(2)));
#endif

// aux_s layout: [0:128) mw1 | [128:224) aw1(rows0-2) | [224:256) ab1
//               [256:288) aw2 | [288:320) mw2 | [320:352) mb1 | [352] mb2 | [353] ab2
__global__ __launch_bounds__(512, 4) void gacq_v6(
    const float* __restrict__ obs,
    const float* __restrict__ mw1, const float* __restrict__ mb1,
    const float* __restrict__ mw2, const float* __restrict__ mb2,
    const float* __restrict__ aw1, const float* __restrict__ ab1,
    const float* __restrict__ aw2, const float* __restrict__ ab2,
    const float* __restrict__ cw1, const float* __restrict__ cb1,
    const float* __restrict__ cw2, const float* __restrict__ cb2,
    const float* __restrict__ cw3, const float* __restrict__ cb3,
    const float* __restrict__ cw4, const float* __restrict__ cb4,
    float* __restrict__ out)
{
    __shared__ __align__(16) float aux_s[356];
    __shared__ __align__(16) float obs_s[NN];
#ifdef USE_F16DOT
    __shared__ __align__(16) _Float16 vh_s[NN][HH];       // 8 KB, f16 v
#else
    __shared__ __align__(16) float vf_s[NN][HH];          // 16 KB fallback
#endif
    __shared__ __align__(16) float p_s[NN][HH];           // swizzled p for stage 2
    __shared__ __align__(16) float part_s[4][8][16][8];   // [jg][kg][rg][rr]
    __shared__ __align__(16) float msg_s[NN];
    __shared__ __align__(16) float cpart_s[8][MIDD];      // critic k-split partials
    __shared__ __align__(16) float h_s[2][MIDD];
    __shared__ float red_s[4];

    const int blk = blockIdx.x;
    const int t   = threadIdx.x;

    if (blk < BB) {
        // ===================== messenger + actor (one b per block) =====================
        const int b = blk;

        if (t < 354) {
            float v;
            if      (t < 128) v = mw1[t];
            else if (t < 224) v = aw1[t - 128];
            else if (t < 256) v = ab1[t - 224];
            else if (t < 288) v = aw2[t - 256];
            else if (t < 320) v = mw2[t - 288];
            else if (t < 352) v = mb1[t - 320];
            else if (t == 352) v = mb2[0];
            else               v = ab2[0];
            aux_s[t] = v;
        }
        if (t < NN) obs_s[t] = obs[b * NN + t];
        __syncthreads();

        // v[j][k] = obs[j]*mw1[2][k] + coor_j*mw1[3][k] + mb1[k]
#ifdef USE_F16DOT
        for (int e = t; e < NN * HH / 2; e += 512) {      // one half2 per iter
            const int   j  = e >> 4, kp = e & 15;
            const int   k0 = kp * 2;
            const float cj = (float)j * (1.0f / (float)NN);
            const float v0 = obs_s[j] * aux_s[64 + k0]     + cj * aux_s[96 + k0]     + aux_s[320 + k0];
            const float v1 = obs_s[j] * aux_s[64 + k0 + 1] + cj * aux_s[96 + k0 + 1] + aux_s[320 + k0 + 1];
            h2_t p; p[0] = (_Float16)v0; p[1] = (_Float16)v1;
            *(h2_t*)&vh_s[j][k0] = p;
        }
#else
        for (int e = t; e < NN * HH; e += 512) {
            const int j = e >> 5, k = e & 31;
            vf_s[j][k] = obs_s[j] * aux_s[64 + k]
                       + ((float)j * (1.0f / (float)NN)) * aux_s[96 + k]
                       + aux_s[320 + k];
        }
#endif

        const int kg = t & 7;           // k = kg*4 + kk
        const int rg = (t >> 3) & 15;   // rows rg*8 + rr
        const int jg = t >> 7;          // j in [jg*32, jg*32+32)

#ifdef USE_F16DOT
        h2_t u2[8][2], w2h[2];
        {
            float wtmp[4];
#pragma unroll
            for (int kk = 0; kk < 4; ++kk) wtmp[kk] = aux_s[288 + kg * 4 + kk];
            w2h[0][0] = (_Float16)wtmp[0]; w2h[0][1] = (_Float16)wtmp[1];
            w2h[1][0] = (_Float16)wtmp[2]; w2h[1][1] = (_Float16)wtmp[3];
        }
#pragma unroll
        for (int rr = 0; rr < 8; ++rr) {
            const int   row = rg * 8 + rr;
            const float ob  = obs_s[row];
            const float cr  = (float)row * (1.0f / (float)NN);
#pragma unroll
            for (int kp = 0; kp < 2; ++kp) {
                const int k0 = kg * 4 + kp * 2;
                const float u0 = ob * aux_s[k0]     + cr * aux_s[32 + k0];
                const float u1 = ob * aux_s[k0 + 1] + cr * aux_s[32 + k0 + 1];
                u2[rr][kp][0] = (_Float16)u0; u2[rr][kp][1] = (_Float16)u1;
            }
        }
#else
        float u[8][4];
        const float w20 = aux_s[288 + kg * 4 + 0];
        const float w21 = aux_s[288 + kg * 4 + 1];
        const float w22 = aux_s[288 + kg * 4 + 2];
        const float w23 = aux_s[288 + kg * 4 + 3];
#pragma unroll
        for (int rr = 0; rr < 8; ++rr) {
            const int   row = rg * 8 + rr;
            const float ob  = obs_s[row];
            const float cr  = (float)row * (1.0f / (float)NN);
#pragma unroll
            for (int kk = 0; kk < 4; ++kk)
                u[rr][kk] = ob * aux_s[kg * 4 + kk] + cr * aux_s[32 + kg * 4 + kk];
        }
#endif
        __syncthreads();   // v ready

        // ---- stage 1: 8 rows x 4 k x 32 j, software-pipelined LDS read ----
        float acc[8];
#pragma unroll
        for (int rr = 0; rr < 8; ++rr) acc[rr] = 0.f;
        const int j0 = jg * 32;
#ifdef USE_F16DOT
        {
            const h2_t zero = (h2_t)((_Float16)0);
            const uint2* vbase = (const uint2*)&vh_s[0][kg * 4];   // row stride = 8 uint2
            uint2 vc = vbase[j0 * 8];
#pragma unroll 4
            for (int jj = 0; jj < 32; ++jj) {
                const int   nj = j0 + ((jj + 1) & 31);
                const uint2 vn = vbase[nj * 8];
                const h2_t  va = __builtin_bit_cast(h2_t, vc.x);
                const h2_t  vb = __builtin_bit_cast(h2_t, vc.y);
#pragma unroll
                for (int rr = 0; rr < 8; ++rr) {
                    h2_t s0 = u2[rr][0] + va;
                    h2_t s1 = u2[rr][1] + vb;
                    s0 = __builtin_elementwise_max(s0, zero);
                    s1 = __builtin_elementwise_max(s1, zero);
                    acc[rr] = __builtin_amdgcn_fdot2(s0, w2h[0], acc[rr], false);
                    acc[rr] = __builtin_amdgcn_fdot2(s1, w2h[1], acc[rr], false);
                }
                vc = vn;
            }
        }
#else
        {
            const float* vbase = &vf_s[0][kg * 4];
            float4 vc = *(const float4*)(vbase + j0 * HH);
#pragma unroll 4
            for (int jj = 0; jj < 32; ++jj) {
                const int    nj = j0 + ((jj + 1) & 31);
                const float4 vn = *(const float4*)(vbase + nj * HH);
#pragma unroll
                for (int rr = 0; rr < 8; ++rr) {
                    acc[rr] += fmaxf(u[rr][0] + vc.x, 0.f) * w20;
                    acc[rr] += fmaxf(u[rr][1] + vc.y, 0.f) * w21;
                    acc[rr] += fmaxf(u[rr][2] + vc.z, 0.f) * w22;
                    acc[rr] += fmaxf(u[rr][3] + vc.w, 0.f) * w23;
                }
                vc = vn;
            }
        }
#endif
        *(float4*)&part_s[jg][kg][rg][0] = make_float4(acc[0], acc[1], acc[2], acc[3]);
        *(float4*)&part_s[jg][kg][rg][4] = make_float4(acc[4], acc[5], acc[6], acc[7]);
        __syncthreads();

        if (t < NN) {
            float m = (float)NN * aux_s[352];
#pragma unroll
            for (int g = 0; g < 4; ++g)
#pragma unroll
                for (int q = 0; q < 8; ++q)
                    m += part_s[g][q][t >> 3][t & 7];
            msg_s[t] = m;
        }
        __syncthreads();

        // ---- stage p: p[row][k] chunk-XOR-swizzled into p_s ----
#pragma unroll
        for (int it = 0; it < 2; ++it) {
            const int   row = t & 127;
            const int   c   = (t >> 7) + it * 4;
            const float mi  = msg_s[row];
            const float cr  = (float)row * (1.0f / (float)NN);
            const int   k0  = c * 4;
            float4 p;
            p.x = mi * aux_s[128 + k0 + 0] + cr * aux_s[160 + k0 + 0] + aux_s[224 + k0 + 0];
            p.y = mi * aux_s[128 + k0 + 1] + cr * aux_s[160 + k0 + 1] + aux_s[224 + k0 + 1];
            p.z = mi * aux_s[128 + k0 + 2] + cr * aux_s[160 + k0 + 2] + aux_s[224 + k0 + 2];
            p.w = mi * aux_s[128 + k0 + 3] + cr * aux_s[160 + k0 + 3] + aux_s[224 + k0 + 3];
            *(float4*)&p_s[row][(c ^ (row & 7)) * 4] = p;
        }
        __syncthreads();

        // ---- stage 2: a = t>>5 (16 groups, a=15 dummy), sub = t&31, rows sub+32m ----
        {
            const int   a   = t >> 5;
            const int   sub = t & 31;
            const float fa  = (float)a;
            float qa[HH];
#pragma unroll
            for (int k = 0; k < HH; ++k) qa[k] = fa * aux_s[192 + k];
            float s0 = 0.f, s1 = 0.f, s2 = 0.f, s3 = 0.f;
#pragma unroll
            for (int m = 0; m < 4; ++m) {
                const int row = sub + 32 * m;
                const int sw  = row & 7;
#pragma unroll
                for (int c = 0; c < 8; ++c) {
                    const float4 p4 = *(const float4*)&p_s[row][(c ^ sw) * 4];
                    const float4 w4 = *(const float4*)&aux_s[256 + c * 4];
                    const int    k0 = c * 4;
                    s0 += fmaxf(p4.x + qa[k0 + 0], 0.f) * w4.x;
                    s1 += fmaxf(p4.y + qa[k0 + 1], 0.f) * w4.y;
                    s2 += fmaxf(p4.z + qa[k0 + 2], 0.f) * w4.z;
                    s3 += fmaxf(p4.w + qa[k0 + 3], 0.f) * w4.w;
                }
            }
            float s = (s0 + s1) + (s2 + s3);
#pragma unroll
            for (int off = 1; off < 32; off <<= 1) s += __shfl_xor(s, off);
            if (sub == 0 && a < AA)
                out[b * AA + a] = s + (float)NN * aux_s[353];
        }
    } else {
        // ===================== critic (one b per block, k-split) =====================
        const int b = blk - BB;
        if (t < NN) obs_s[t] = obs[b * NN + t];
        __syncthreads();

        const int q = t & 63;     // output quad: units 4q..4q+3
        const int s = t >> 6;     // k-slice

        {   // layer 1: 128 -> 256, k-slice of 16
            float4 acc = make_float4(0.f, 0.f, 0.f, 0.f);
            const int k0 = s * 16;
#pragma unroll 8
            for (int k = k0; k < k0 + 16; ++k) {
                const float4 w = *(const float4*)&cw1[k * MIDD + q * 4];
                const float  h = obs_s[k];
                acc.x += h * w.x; acc.y += h * w.y; acc.z += h * w.z; acc.w += h * w.w;
            }
            *(float4*)&cpart_s[s][q * 4] = acc;
        }
        __syncthreads();
        if (t < MIDD) {
            float sum = cb1[t];
#pragma unroll
            for (int s8 = 0; s8 < 8; ++s8) sum += cpart_s[s8][t];
            h_s[0][t] = fmaxf(sum, 0.f);
        }
        __syncthreads();

        {   // layer 2: 256 -> 256, k-slice of 32
            float4 acc = make_float4(0.f, 0.f, 0.f, 0.f);
            const int k0 = s * 32;
#pragma unroll 8
            for (int k = k0; k < k0 + 32; ++k) {
                const float4 w = *(const float4*)&cw2[k * MIDD + q * 4];
                const float  h = h_s[0][k];
                acc.x += h * w.x; acc.y += h * w.y; acc.z += h * w.z; acc.w += h * w.w;
            }
            *(float4*)&cpart_s[s][q * 4] = acc;
        }
        __syncthreads();
        if (t < MIDD) {
            float sum = cb2[t];
#pragma unroll
            for (int s8 = 0; s8 < 8; ++s8) sum += cpart_s[s8][t];
            h_s[1][t] = fmaxf(sum, 0.f);
        }
        __syncthreads();

        {   // layer 3: 256 -> 256, k-slice of 32
            float4 acc = make_float4(0.f, 0.f, 0.f, 0.f);
            const int k0 = s * 32;
#pragma unroll 8
            for (int k = k0; k < k0 + 32; ++k) {
                const float4 w = *(const float4*)&cw3[k * MIDD + q * 4];
                const float  h = h_s[1][k];
                acc.x += h * w.x; acc.y += h * w.y; acc.z += h * w.z; acc.w += h * w.w;
            }
            *(float4*)&cpart_s[s][q * 4] = acc;
        }
        __syncthreads();
        if (t < MIDD) {   // layer-3 finish + head
            float sum = cb3[t];
#pragma unroll
            for (int s8 = 0; s8 < 8; ++s8) sum += cpart_s[s8][t];
            const float h3 = fmaxf(sum, 0.f);
            float pv = h3 * cw4[t];
#pragma unroll
            for (int off = 32; off > 0; off >>= 1) pv += __shfl_xor(pv, off);
            if ((t & 63) == 0) red_s[t >> 6] = pv;
        }
        __syncthreads();
        if (t == 0)
            out[BB * AA + b] = red_s[0] + red_s[1] + red_s[2] + red_s[3] + cb4[0];
    }
}

extern "C" void kernel_launch(void* const* d_in, const int* in_sizes, int n_in,
                              void* d_out, int out_size, void* d_ws, size_t ws_size,
                              hipStream_t stream) {
    const float* obs = (const float*)d_in[0];
    const float* mw1 = (const float*)d_in[1];
    const float* mb1 = (const float*)d_in[2];
    const float* mw2 = (const float*)d_in[3];
    const float* mb2 = (const float*)d_in[4];
    const float* aw1 = (const float*)d_in[5];
    const float* ab1 = (const float*)d_in[6];
    const float* aw2 = (const float*)d_in[7];
    const float* ab2 = (const float*)d_in[8];
    const float* cw1 = (const float*)d_in[9];
    const float* cb1 = (const float*)d_in[10];
    const float* cw2 = (const float*)d_in[11];
    const float* cb2 = (const float*)d_in[12];
    const float* cw3 = (const float*)d_in[13];
    const float* cb3 = (const float*)d_in[14];
    const float* cw4 = (const float*)d_in[15];
    const float* cb4 = (const float*)d_in[16];
    float* out = (float*)d_out;

    gacq_v6<<<dim3(2 * BB), dim3(512), 0, stream>>>(
        obs, mw1, mb1, mw2, mb2, aw1, ab1, aw2, ab2,
        cw1, cb1, cw2, cb2, cw3, cb3, cw4, cb4, out);
}